// Round 4
// baseline (241.732 us; speedup 1.0000x reference)
//
#include <hip/hip_runtime.h>
#include <stdint.h>

#define B_ 32
#define T_ 4096
#define D_ 512
#define BT_ (B_*T_)

typedef __attribute__((ext_vector_type(8))) short bf16x8;
typedef __attribute__((ext_vector_type(4))) float f32x4;

__device__ __forceinline__ unsigned short f2bf(float f) {
    unsigned int u = __float_as_uint(f);
    u += 0x7FFFu + ((u >> 16) & 1u);   // round-to-nearest-even (inputs are finite)
    return (unsigned short)(u >> 16);
}

__device__ __forceinline__ float tanh_fast(float x) {
    float e2 = __expf(2.0f * x);       // inf for large x, 0 for very negative -> correct limits
    return 1.0f - 2.0f / (e2 + 1.0f);
}

// ---------------------------------------------------------------------------
// W_h (D x D fp32, [k][n]) -> bf16 MFMA B-fragment layout in ws:
//   wsb[((nt*16+kt)*64 + l)*8 + j] = bf16(W_h[kt*32 + (l>>4)*8 + j][nt*16 + (l&15)])
__global__ __launch_bounds__(256) void k_conv_wh(const float* __restrict__ W_h,
                                                 unsigned short* __restrict__ wsb) {
    int tid = blockIdx.x * 256 + threadIdx.x;   // 0..32767
    int l  = tid & 63;
    int kt = (tid >> 6) & 15;
    int nt = tid >> 10;
    int n  = nt * 16 + (l & 15);
    int k0 = kt * 32 + (l >> 4) * 8;
    unsigned int w[4];
#pragma unroll
    for (int q = 0; q < 4; ++q) {
        unsigned short lo = f2bf(W_h[(size_t)(k0 + 2*q)     * D_ + n]);
        unsigned short hi = f2bf(W_h[(size_t)(k0 + 2*q + 1) * D_ + n]);
        w[q] = (unsigned int)lo | ((unsigned int)hi << 16);
    }
    uint4 pk = {w[0], w[1], w[2], w[3]};
    ((uint4*)wsb)[tid] = pk;
}

// ---------------------------------------------------------------------------
// dec[b][c] = b_s[c] + sum_k s_t[b][k] * W_s[k][c]
__global__ __launch_bounds__(256) void k_dec(const float* __restrict__ s_t,
                                             const float* __restrict__ W_s,
                                             const float* __restrict__ b_s,
                                             float* __restrict__ dec) {
    int b = blockIdx.x;
    int c = threadIdx.x;
    float a0 = b_s[c], a1 = b_s[c + 256];
    const float* srow = s_t + b * D_;
    for (int k = 0; k < D_; ++k) {
        float s = srow[k];
        const float* wr = W_s + (size_t)k * D_;
        a0 = fmaf(s, wr[c], a0);
        a1 = fmaf(s, wr[c + 256], a1);
    }
    dec[b * D_ + c] = a0;
    dec[b * D_ + c + 256] = a1;
}

// ---------------------------------------------------------------------------
// Main fused kernel. Block = 64 rows of (B*T), 8 waves (512 threads).
// K split into 2 halves of 256, double-buffered LDS (2 x 32 KB).
// Pipeline: stage h0 | issue h1 loads | BAR | compute h0 (B 2-deep prefetch)
//           | write h1 | BAR | compute h1 | epilogue.
// Raw s_barrier + lgkmcnt(0) (no vmcnt drain) keeps h1 loads in flight
// across the barrier, hiding HBM latency under half0's MFMA.
// LDS frag layout per half: frag (af,ktl) at (af*8+ktl)*1024; element lam at
// slot sigma(lam,ktl) = (lam&0x38)|((lam&7)^((lam>>4&3)<<1)^(ktl&1)).
__global__ __launch_bounds__(512, 4) void k_main(const float* __restrict__ h_i,
                                                 const float* __restrict__ coverage,
                                                 const unsigned short* __restrict__ wsb,
                                                 const float* __restrict__ dec,
                                                 const float* __restrict__ W_c,
                                                 const float* __restrict__ V,
                                                 float* __restrict__ e_out) {
    __shared__ __align__(16) unsigned char As[65536];   // 2 x 32KB halves
    __shared__ float red[8][64];
    const int tid = threadIdx.x;
    const int w = tid >> 6, l = tid & 63;
    const int row0 = blockIdx.x * 64;           // flat (b*T + t), 64-aligned
    const int b    = row0 >> 12;
    const int t0   = row0 & (T_ - 1);

    // staging-side invariants for this thread
    const int s_ktl  = l >> 3;                              // frag k-slot from lane
    const int s_m    = ((l >> 1) & 3);                      // lam>>4 bits
    const int s_bits = (s_m << 4) | (w ^ (s_m << 1) ^ (l >> 3 & 1)); // row&7 == w
    const int s_off  = (s_ktl << 10) + ((l & 1) << 3);

    // read-side slot (kt-even; XOR 1 for odd kt)
    const int slotR = (l & 0x38) | ((l & 7) ^ (((l >> 4) & 3) << 1));

    const uint4* bw = (const uint4*)wsb + ((w * 4) << 10) + l;   // + j*1024 + ktg*64

    f32x4 acc[4][4];                            // [af][j]
#pragma unroll
    for (int af = 0; af < 4; ++af)
#pragma unroll
        for (int j = 0; j < 4; ++j) acc[af][j] = (f32x4){0, 0, 0, 0};

    // ---- load half0 (coalesced: 8 x float4 per thread, 1KB per wave-instr)
    float4 L[8];
#pragma unroll
    for (int i = 0; i < 8; ++i)
        L[i] = *(const float4*)(h_i + (size_t)(row0 + i * 8 + w) * D_ + l * 4);

    // convert + swizzled LDS write, half0
    unsigned char* A0 = As;
    unsigned char* A1 = As + 32768;
#pragma unroll
    for (int i = 0; i < 8; ++i) {
        uint2 pk;
        pk.x = (unsigned)f2bf(L[i].x) | ((unsigned)f2bf(L[i].y) << 16);
        pk.y = (unsigned)f2bf(L[i].z) | ((unsigned)f2bf(L[i].w) << 16);
        int slot = ((i & 1) << 3) | s_bits;
        int byte = (((i >> 1) << 13)) + (slot << 4) + s_off;   // (af*8+ktl)*1024 + ...
        *(uint2*)(A0 + byte) = pk;
    }

    // ---- issue half1 loads NOW; they stay in flight across the raw barrier
    float4 M[8];
#pragma unroll
    for (int i = 0; i < 8; ++i)
        M[i] = *(const float4*)(h_i + (size_t)(row0 + i * 8 + w) * D_ + 256 + l * 4);

    asm volatile("s_waitcnt lgkmcnt(0)" ::: "memory");
    __builtin_amdgcn_s_barrier();

    // ---- compute one K-half from LDS buffer Ab, ktg base h*8
    auto compute = [&](const unsigned char* Ab, int h8) {
        uint4 bp[2][4];
#pragma unroll
        for (int j = 0; j < 4; ++j) bp[0][j] = bw[(j << 10) + ((h8 + 0) << 6)];
#pragma unroll
        for (int j = 0; j < 4; ++j) bp[1][j] = bw[(j << 10) + ((h8 + 1) << 6)];
#pragma unroll
        for (int ktl = 0; ktl < 8; ++ktl) {
            const int sl = ((slotR ^ (ktl & 1)) << 4);
#pragma unroll
            for (int af = 0; af < 4; ++af) {
                uint4 araw = *(const uint4*)(Ab + ((af * 8 + ktl) << 10) + sl);
                bf16x8 a = __builtin_bit_cast(bf16x8, araw);
#pragma unroll
                for (int j = 0; j < 4; ++j) {
                    bf16x8 bv = __builtin_bit_cast(bf16x8, bp[ktl & 1][j]);
                    acc[af][j] = __builtin_amdgcn_mfma_f32_16x16x32_bf16(a, bv, acc[af][j], 0, 0, 0);
                }
            }
            if (ktl < 6) {
#pragma unroll
                for (int j = 0; j < 4; ++j)
                    bp[ktl & 1][j] = bw[(j << 10) + ((h8 + ktl + 2) << 6)];
            }
        }
    };

    compute(A0, 0);

    // convert + write half1 (compiler inserts the counted vmcnt for M)
#pragma unroll
    for (int i = 0; i < 8; ++i) {
        uint2 pk;
        pk.x = (unsigned)f2bf(M[i].x) | ((unsigned)f2bf(M[i].y) << 16);
        pk.y = (unsigned)f2bf(M[i].z) | ((unsigned)f2bf(M[i].w) << 16);
        int slot = ((i & 1) << 3) | s_bits;
        int byte = (((i >> 1) << 13)) + (slot << 4) + s_off;
        *(uint2*)(A1 + byte) = pk;
    }
    asm volatile("s_waitcnt lgkmcnt(0)" ::: "memory");
    __builtin_amdgcn_s_barrier();

    compute(A1, 8);

    // ---- epilogue: tanh + dot with V over this wave's 64 cols
    const int rgrp = (l >> 4) * 4;
    float cov_r[4][4];
#pragma unroll
    for (int af = 0; af < 4; ++af)
#pragma unroll
        for (int r = 0; r < 4; ++r)
            cov_r[af][r] = coverage[b * T_ + t0 + af * 16 + rgrp + r];

    float p[4][4] = {{0,0,0,0},{0,0,0,0},{0,0,0,0},{0,0,0,0}};  // [af][r]
#pragma unroll
    for (int j = 0; j < 4; ++j) {
        int col = w * 64 + j * 16 + (l & 15);
        float dv = dec[b * D_ + col];
        float wc = W_c[col];
        float vv = V[col];
#pragma unroll
        for (int af = 0; af < 4; ++af)
#pragma unroll
            for (int r = 0; r < 4; ++r) {
                float x = acc[af][j][r] + dv + cov_r[af][r] * wc;
                p[af][r] += tanh_fast(x) * vv;
            }
    }

    // reduce across the 16 lanes sharing each row (lane bits 0..3)
#pragma unroll
    for (int m = 1; m <= 8; m <<= 1)
#pragma unroll
        for (int af = 0; af < 4; ++af)
#pragma unroll
            for (int r = 0; r < 4; ++r)
                p[af][r] += __shfl_xor(p[af][r], m, 64);
    if ((l & 15) == 0) {
#pragma unroll
        for (int af = 0; af < 4; ++af)
#pragma unroll
            for (int r = 0; r < 4; ++r)
                red[w][af * 16 + rgrp + r] = p[af][r];
    }
    __syncthreads();
    if (tid < 64) {
        float e = red[0][tid] + red[1][tid] + red[2][tid] + red[3][tid]
                + red[4][tid] + red[5][tid] + red[6][tid] + red[7][tid];
        e_out[b * T_ + t0 + tid] = e;
    }
}

// ---------------------------------------------------------------------------
// Softmax over T per batch + new_coverage.
__global__ __launch_bounds__(256) void k_soft(const float* __restrict__ e_in,
                                              const float* __restrict__ coverage,
                                              float* __restrict__ out_at,
                                              float* __restrict__ out_cov) {
    int b = blockIdx.x, tid = threadIdx.x;
    __shared__ float red[4];
    float v[16];
    float m = -1e30f;
#pragma unroll
    for (int i = 0; i < 16; ++i) {
        v[i] = e_in[b * T_ + tid + i * 256];
        m = fmaxf(m, v[i]);
    }
#pragma unroll
    for (int mk = 1; mk <= 32; mk <<= 1) m = fmaxf(m, __shfl_xor(m, mk, 64));
    if ((tid & 63) == 0) red[tid >> 6] = m;
    __syncthreads();
    m = fmaxf(fmaxf(red[0], red[1]), fmaxf(red[2], red[3]));
    float s = 0.f;
#pragma unroll
    for (int i = 0; i < 16; ++i) { v[i] = expf(v[i] - m); s += v[i]; }
#pragma unroll
    for (int mk = 1; mk <= 32; mk <<= 1) s += __shfl_xor(s, mk, 64);
    __syncthreads();
    if ((tid & 63) == 0) red[tid >> 6] = s;
    __syncthreads();
    s = red[0] + red[1] + red[2] + red[3];
    float inv = 1.0f / s;
#pragma unroll
    for (int i = 0; i < 16; ++i) {
        int idx = b * T_ + tid + i * 256;
        float a = v[i] * inv;
        out_at[idx]  = a;
        out_cov[idx] = coverage[idx] + a;
    }
}

// ---------------------------------------------------------------------------
// context partials
__global__ __launch_bounds__(256) void k_ctx(const float* __restrict__ h_i,
                                             const float* __restrict__ a_t,
                                             float* __restrict__ part) {
    int blk = blockIdx.x;           // 0..2047
    int b = blk >> 6, s = blk & 63;
    int d0 = threadIdx.x * 2;
    const size_t base = ((size_t)b * T_ + (size_t)s * 64) * D_;
    const float* at = a_t + b * T_ + s * 64;
    float2 acc = {0.f, 0.f};
    for (int t = 0; t < 64; ++t) {
        float a = at[t];
        float2 h2 = *(const float2*)(h_i + base + (size_t)t * D_ + d0);
        acc.x = fmaf(a, h2.x, acc.x);
        acc.y = fmaf(a, h2.y, acc.y);
    }
    float* pp = part + (size_t)blk * D_ + d0;
    pp[0] = acc.x;
    pp[1] = acc.y;
}

__global__ __launch_bounds__(256) void k_comb(const float* __restrict__ part,
                                              float* __restrict__ out_ctx) {
    int idx = blockIdx.x * 256 + threadIdx.x;   // 0..16383
    int b = idx >> 9, d = idx & 511;
    const float* pp = part + (size_t)b * 64 * D_ + d;
    float s = 0.f;
#pragma unroll 8
    for (int j = 0; j < 64; ++j) s += pp[(size_t)j * D_];
    out_ctx[idx] = s;
}

// ---------------------------------------------------------------------------
extern "C" void kernel_launch(void* const* d_in, const int* in_sizes, int n_in,
                              void* d_out, int out_size, void* d_ws, size_t ws_size,
                              hipStream_t stream) {
    const float* h_i      = (const float*)d_in[0];
    const float* s_t      = (const float*)d_in[1];
    const float* coverage = (const float*)d_in[2];
    const float* W_h      = (const float*)d_in[3];
    const float* W_s      = (const float*)d_in[4];
    const float* b_s      = (const float*)d_in[5];
    const float* W_c      = (const float*)d_in[6];
    const float* V        = (const float*)d_in[7];

    float* out_ctx = (float*)d_out;             // B*D
    float* out_at  = out_ctx + B_ * D_;         // B*T (holds e_t between k_main and k_soft)
    float* out_cov = out_at + BT_;              // B*T

    unsigned short* wsb = (unsigned short*)d_ws;              // 512 KB bf16 W_h frags
    float* dec  = (float*)((char*)d_ws + 524288);             // 64 KB
    float* part = dec + B_ * D_;                              // 4 MB

    k_conv_wh<<<128, 256, 0, stream>>>(W_h, wsb);
    k_dec<<<B_, 256, 0, stream>>>(s_t, W_s, b_s, dec);
    k_main<<<BT_ / 64, 512, 0, stream>>>(h_i, coverage, wsb, dec, W_c, V, out_at);
    k_soft<<<B_, 256, 0, stream>>>(out_at, coverage, out_at, out_cov);
    k_ctx<<<B_ * 64, 256, 0, stream>>>(h_i, out_at, part);
    k_comb<<<B_ * D_ / 256, 256, 0, stream>>>(part, out_ctx);
}

// Round 5
// 168.377 us; speedup vs baseline: 1.4357x; 1.4357x over previous
//
#include <hip/hip_runtime.h>
#include <stdint.h>

#define B_ 32
#define T_ 4096
#define D_ 512
#define BT_ (B_*T_)

typedef __attribute__((ext_vector_type(8))) short bf16x8;
typedef __attribute__((ext_vector_type(4))) float f32x4;

__device__ __forceinline__ unsigned short f2bf(float f) {
    unsigned int u = __float_as_uint(f);
    u += 0x7FFFu + ((u >> 16) & 1u);   // round-to-nearest-even (inputs are finite)
    return (unsigned short)(u >> 16);
}

__device__ __forceinline__ float tanh_fast(float x) {
    float e2 = __expf(2.0f * x);       // inf for large x, 0 for very negative -> correct limits
    return 1.0f - 2.0f / (e2 + 1.0f);
}

// ---------------------------------------------------------------------------
// W_h (D x D fp32, [k][n]) -> bf16 MFMA B-fragment layout in ws:
//   wsb[((nt*16+kt)*64 + l)*8 + j] = bf16(W_h[kt*32 + (l>>4)*8 + j][nt*16 + (l&15)])
__global__ __launch_bounds__(256) void k_conv_wh(const float* __restrict__ W_h,
                                                 unsigned short* __restrict__ wsb) {
    int tid = blockIdx.x * 256 + threadIdx.x;   // 0..32767
    int l  = tid & 63;
    int kt = (tid >> 6) & 15;
    int nt = tid >> 10;
    int n  = nt * 16 + (l & 15);
    int k0 = kt * 32 + (l >> 4) * 8;
    unsigned int w[4];
#pragma unroll
    for (int q = 0; q < 4; ++q) {
        unsigned short lo = f2bf(W_h[(size_t)(k0 + 2*q)     * D_ + n]);
        unsigned short hi = f2bf(W_h[(size_t)(k0 + 2*q + 1) * D_ + n]);
        w[q] = (unsigned int)lo | ((unsigned int)hi << 16);
    }
    uint4 pk = {w[0], w[1], w[2], w[3]};
    ((uint4*)wsb)[tid] = pk;
}

// ---------------------------------------------------------------------------
// dec[b][c] = b_s[c] + sum_k s_t[b][k] * W_s[k][c]
__global__ __launch_bounds__(256) void k_dec(const float* __restrict__ s_t,
                                             const float* __restrict__ W_s,
                                             const float* __restrict__ b_s,
                                             float* __restrict__ dec) {
    int b = blockIdx.x;
    int c = threadIdx.x;
    float a0 = b_s[c], a1 = b_s[c + 256];
    const float* srow = s_t + b * D_;
    for (int k = 0; k < D_; ++k) {
        float s = srow[k];
        const float* wr = W_s + (size_t)k * D_;
        a0 = fmaf(s, wr[c], a0);
        a1 = fmaf(s, wr[c + 256], a1);
    }
    dec[b * D_ + c] = a0;
    dec[b * D_ + c + 256] = a1;
}

// ---------------------------------------------------------------------------
// Main fused kernel. Block = 64 rows of (B*T), 8 waves (512 threads).
// A panel (64 rows x 512 K, bf16) staged once in LDS (sigma-swizzled frag
// layout, conflict-free both sides), shared by all 8 waves. Wave w computes
// output cols [w*64, w*64+64). After the e_t reduction, the block ALSO
// computes its context partial  part[blk][d] = sum_t exp(e_t) * h[t][d]
// from the SAME LDS panel (kills the separate k_ctx 256MB re-read).
// exp is unshifted: |e_t| <= sum|V_n| ~ 20  ->  exp <= ~1e11, fp32-safe.
__global__ __launch_bounds__(512, 4) void k_main(const float* __restrict__ h_i,
                                                 const float* __restrict__ coverage,
                                                 const unsigned short* __restrict__ wsb,
                                                 const float* __restrict__ dec,
                                                 const float* __restrict__ W_c,
                                                 const float* __restrict__ V,
                                                 float* __restrict__ e_out,
                                                 float* __restrict__ part) {
    __shared__ __align__(16) unsigned char As[65536];
    __shared__ float red[8][64];
    __shared__ float wexp[64];
    const int tid = threadIdx.x;
    const int w = tid >> 6, l = tid & 63;
    const int row0 = blockIdx.x * 64;           // flat (b*T + t), 64-aligned
    const int b    = row0 >> 12;
    const int t0   = row0 & (T_ - 1);

    // ---- stage A: issue ALL 16 global loads first (MLP), then convert+write.
    // L0/L1 die at the LDS writes, before acc goes live -> no spill.
    float4 L0[8], L1[8];
#pragma unroll
    for (int i = 0; i < 8; ++i) {
        const float* src = h_i + (size_t)(row0 + i * 8 + w) * D_ + l * 8;
        L0[i] = *(const float4*)(src);
        L1[i] = *(const float4*)(src + 4);
    }
    {
        const int kt   = l >> 2;
        const int lam  = 16 * (l & 3);          // + (row&15); row&15 == (i*8+w)&15
        const int sl_m = (l & 3) << 1;
#pragma unroll
        for (int i = 0; i < 8; ++i) {
            int row = i * 8 + w;
            uint4 pk;
            pk.x = (unsigned)f2bf(L0[i].x) | ((unsigned)f2bf(L0[i].y) << 16);
            pk.y = (unsigned)f2bf(L0[i].z) | ((unsigned)f2bf(L0[i].w) << 16);
            pk.z = (unsigned)f2bf(L1[i].x) | ((unsigned)f2bf(L1[i].y) << 16);
            pk.w = (unsigned)f2bf(L1[i].z) | ((unsigned)f2bf(L1[i].w) << 16);
            int lamf = lam + (row & 15);
            int slot = (lamf & 0x38) | ((lamf & 7) ^ sl_m ^ (kt & 1));
            int byte = (((row >> 4) * 16 + kt) << 10) + (slot << 4);
            *(uint4*)(As + byte) = pk;
        }
    }
    __syncthreads();

    // read-side slot (kt-even; XOR 1 for odd kt)
    const int slotR = (l & 0x38) | ((l & 7) ^ (((l >> 4) & 3) << 1));

    f32x4 acc[4][4];                            // [af][j]
#pragma unroll
    for (int af = 0; af < 4; ++af)
#pragma unroll
        for (int j = 0; j < 4; ++j) acc[af][j] = (f32x4){0, 0, 0, 0};

    const uint4* bw = (const uint4*)wsb + ((w * 4) << 10) + l;   // + j*1024 + kt*64

    {   // ---- K loop with 2-deep B prefetch (all indices compile-time)
        uint4 bp[2][4];
#pragma unroll
        for (int j = 0; j < 4; ++j) bp[0][j] = bw[(j << 10)];
#pragma unroll
        for (int j = 0; j < 4; ++j) bp[1][j] = bw[(j << 10) + (1 << 6)];
#pragma unroll
        for (int kt = 0; kt < 16; ++kt) {
            const int sl = ((slotR ^ (kt & 1)) << 4);
#pragma unroll
            for (int af = 0; af < 4; ++af) {
                uint4 araw = *(const uint4*)(As + ((af * 16 + kt) << 10) + sl);
                bf16x8 a = __builtin_bit_cast(bf16x8, araw);
#pragma unroll
                for (int j = 0; j < 4; ++j) {
                    bf16x8 bv = __builtin_bit_cast(bf16x8, bp[kt & 1][j]);
                    acc[af][j] = __builtin_amdgcn_mfma_f32_16x16x32_bf16(a, bv, acc[af][j], 0, 0, 0);
                }
            }
            if (kt < 14) {
#pragma unroll
                for (int j = 0; j < 4; ++j)
                    bp[kt & 1][j] = bw[(j << 10) + ((kt + 2) << 6)];
            }
        }
    }

    // ---- epilogue: tanh + dot with V over this wave's 64 cols
    const int rgrp = (l >> 4) * 4;
    float cov_r[4][4];
#pragma unroll
    for (int af = 0; af < 4; ++af)
#pragma unroll
        for (int r = 0; r < 4; ++r)
            cov_r[af][r] = coverage[b * T_ + t0 + af * 16 + rgrp + r];

    float p[4][4] = {{0,0,0,0},{0,0,0,0},{0,0,0,0},{0,0,0,0}};  // [af][r]
#pragma unroll
    for (int j = 0; j < 4; ++j) {
        int col = w * 64 + j * 16 + (l & 15);
        float dv = dec[b * D_ + col];
        float wc = W_c[col];
        float vv = V[col];
#pragma unroll
        for (int af = 0; af < 4; ++af)
#pragma unroll
            for (int r = 0; r < 4; ++r) {
                float x = acc[af][j][r] + dv + cov_r[af][r] * wc;
                p[af][r] += tanh_fast(x) * vv;
            }
    }

    // reduce across the 16 lanes sharing each row (lane bits 0..3)
#pragma unroll
    for (int m = 1; m <= 8; m <<= 1)
#pragma unroll
        for (int af = 0; af < 4; ++af)
#pragma unroll
            for (int r = 0; r < 4; ++r)
                p[af][r] += __shfl_xor(p[af][r], m, 64);
    if ((l & 15) == 0) {
#pragma unroll
        for (int af = 0; af < 4; ++af)
#pragma unroll
            for (int r = 0; r < 4; ++r)
                red[w][af * 16 + rgrp + r] = p[af][r];
    }
    __syncthreads();
    if (tid < 64) {
        float e = red[0][tid] + red[1][tid] + red[2][tid] + red[3][tid]
                + red[4][tid] + red[5][tid] + red[6][tid] + red[7][tid];
        e_out[b * T_ + t0 + tid] = e;
        wexp[tid] = __expf(e);
    }
    __syncthreads();

    // ---- fused context partial: part[blk][d] = sum_t wexp[t] * A[t][d]
    // thread d = tid. Conflict-free: the 8 (m,kt)-lane-groups per wave have
    // distinct slot low-3 bits; within a group 8 lanes span 16B (2-way, free).
    {
        const int d    = tid;
        const int ktg  = d >> 5;
        const int mq   = (d >> 3) & 3;
        const int base2 = ((mq << 4) | (((mq << 1) ^ (ktg & 1)) & 7)) << 4;
        const unsigned char* Ag = As + (ktg << 10) + ((d & 7) << 1);
        float cacc = 0.f;
#pragma unroll
        for (int t = 0; t < 64; ++t) {
            int byte = ((t >> 4) << 14) + (base2 ^ ((t & 15) << 4));
            unsigned short u = *(const unsigned short*)(Ag + byte);
            float hv = __uint_as_float(((unsigned)u) << 16);
            cacc = fmaf(wexp[t], hv, cacc);
        }
        part[(size_t)blockIdx.x * D_ + d] = cacc;
    }
}

// ---------------------------------------------------------------------------
// Softmax over T per batch + new_coverage; also emits S_b = exp(m)*Z for the
// fused context normalization.
__global__ __launch_bounds__(256) void k_soft(const float* __restrict__ e_in,
                                              const float* __restrict__ coverage,
                                              float* __restrict__ out_at,
                                              float* __restrict__ out_cov,
                                              float* __restrict__ Sb) {
    int b = blockIdx.x, tid = threadIdx.x;
    __shared__ float red[4];
    float v[16];
    float m = -1e30f;
#pragma unroll
    for (int i = 0; i < 16; ++i) {
        v[i] = e_in[b * T_ + tid + i * 256];
        m = fmaxf(m, v[i]);
    }
#pragma unroll
    for (int mk = 1; mk <= 32; mk <<= 1) m = fmaxf(m, __shfl_xor(m, mk, 64));
    if ((tid & 63) == 0) red[tid >> 6] = m;
    __syncthreads();
    m = fmaxf(fmaxf(red[0], red[1]), fmaxf(red[2], red[3]));
    float s = 0.f;
#pragma unroll
    for (int i = 0; i < 16; ++i) { v[i] = expf(v[i] - m); s += v[i]; }
#pragma unroll
    for (int mk = 1; mk <= 32; mk <<= 1) s += __shfl_xor(s, mk, 64);
    __syncthreads();
    if ((tid & 63) == 0) red[tid >> 6] = s;
    __syncthreads();
    s = red[0] + red[1] + red[2] + red[3];
    if (tid == 0) Sb[b] = __expf(m) * s;       // sum_t exp(e_t), stable form
    float inv = 1.0f / s;
#pragma unroll
    for (int i = 0; i < 16; ++i) {
        int idx = b * T_ + tid + i * 256;
        float a = v[i] * inv;
        out_at[idx]  = a;
        out_cov[idx] = coverage[idx] + a;
    }
}

// ---------------------------------------------------------------------------
// combine: context[b][d] = (sum_s part[(b*64+s)][d]) / S_b   (deterministic)
__global__ __launch_bounds__(256) void k_comb(const float* __restrict__ part,
                                              const float* __restrict__ Sb,
                                              float* __restrict__ out_ctx) {
    int idx = blockIdx.x * 256 + threadIdx.x;   // 0..16383
    int b = idx >> 9, d = idx & 511;
    const float* pp = part + (size_t)b * 64 * D_ + d;
    float s = 0.f;
#pragma unroll 8
    for (int j = 0; j < 64; ++j) s += pp[(size_t)j * D_];
    out_ctx[idx] = s / Sb[b];
}

// ---------------------------------------------------------------------------
extern "C" void kernel_launch(void* const* d_in, const int* in_sizes, int n_in,
                              void* d_out, int out_size, void* d_ws, size_t ws_size,
                              hipStream_t stream) {
    const float* h_i      = (const float*)d_in[0];
    const float* s_t      = (const float*)d_in[1];
    const float* coverage = (const float*)d_in[2];
    const float* W_h      = (const float*)d_in[3];
    const float* W_s      = (const float*)d_in[4];
    const float* b_s      = (const float*)d_in[5];
    const float* W_c      = (const float*)d_in[6];
    const float* V        = (const float*)d_in[7];

    float* out_ctx = (float*)d_out;             // B*D
    float* out_at  = out_ctx + B_ * D_;         // B*T (holds e_t between k_main and k_soft)
    float* out_cov = out_at + BT_;              // B*T

    unsigned short* wsb = (unsigned short*)d_ws;              // 512 KB bf16 W_h frags
    float* dec  = (float*)((char*)d_ws + 524288);             // 64 KB
    float* part = dec + B_ * D_;                              // 4 MB (2048 x 512)
    float* Sb   = part + (size_t)BT_ / 64 * D_;               // 32 floats

    k_conv_wh<<<128, 256, 0, stream>>>(W_h, wsb);
    k_dec<<<B_, 256, 0, stream>>>(s_t, W_s, b_s, dec);
    k_main<<<BT_ / 64, 512, 0, stream>>>(h_i, coverage, wsb, dec, W_c, V, out_at, part);
    k_soft<<<B_, 256, 0, stream>>>(out_at, coverage, out_at, out_cov, Sb);
    k_comb<<<B_ * D_ / 256, 256, 0, stream>>>(part, Sb, out_ctx);
}